// Round 5
// baseline (213.452 us; speedup 1.0000x reference)
//
#include <hip/hip_runtime.h>
#include <hip/hip_bf16.h>
#include <stdint.h>

// Sizes (fixed by the problem)
#define B_SZ 2
#define S_LEN 2048
#define DM 1024
#define NH 16
#define DEPTH 64
#define M_ROWS (B_SZ * S_LEN)   // 4096
#define SCALE_Q 0.1803368801111144f   // log2(e)/sqrt(DEPTH), folded into Q proj

typedef __attribute__((ext_vector_type(8))) short bf16x8;    // 8 bf16 = 4 VGPRs
typedef __attribute__((ext_vector_type(4))) float f32x4;     // 16x16 C/D frag
typedef __attribute__((ext_vector_type(16))) float f32x16;   // 32x32 C/D frag

__device__ __forceinline__ unsigned short f2bf(float x) {
    union { float f; unsigned u; } a; a.f = x;
    unsigned r = a.u + 0x7FFF + ((a.u >> 16) & 1);   // RTNE
    return (unsigned short)(r >> 16);
}

// async global->LDS, 16B per lane. LDS dest = wave-uniform base + lane*16.
__device__ __forceinline__ void async_ld16(const unsigned short* g, void* l) {
    __builtin_amdgcn_global_load_lds(
        (const __attribute__((address_space(1))) void*)g,
        (__attribute__((address_space(3))) void*)l,
        16, 0, 0);
}

// ===========================================================================
// FAST PATH
// ===========================================================================

// ---------------------------------------------------------------------------
// Kernel 1: fp32 -> bf16 convert (RTNE) of q,k,v,wq,wk,wv into ws.
// ---------------------------------------------------------------------------
__global__ __launch_bounds__(256)
void convert_kernel(const float* __restrict__ q, const float* __restrict__ k,
                    const float* __restrict__ v, const float* __restrict__ wq,
                    const float* __restrict__ wk, const float* __restrict__ wv,
                    unsigned short* __restrict__ dst) {
    const int z = blockIdx.y;
    const float* src = (z == 0) ? q : (z == 1) ? k : (z == 2) ? v
                     : (z == 3) ? wq : (z == 4) ? wk : wv;
    const size_t n4  = (z < 3) ? ((size_t)M_ROWS * DM / 4) : ((size_t)DM * DM / 4);
    const size_t off = (z < 3) ? ((size_t)z * M_ROWS * DM)
                               : ((size_t)3 * M_ROWS * DM + (size_t)(z - 3) * DM * DM);
    unsigned short* d = dst + off;
    const size_t stride = (size_t)gridDim.x * blockDim.x;
    for (size_t i = (size_t)blockIdx.x * blockDim.x + threadIdx.x; i < n4; i += stride) {
        float4 x = ((const float4*)src)[i];
        ushort4 p;
        p.x = f2bf(x.x); p.y = f2bf(x.y); p.z = f2bf(x.z); p.w = f2bf(x.w);
        ((ushort4*)d)[i] = p;
    }
}

// ---------------------------------------------------------------------------
// Kernel 2: bf16 NT GEMM with 32x32x16 MFMA. 128x128 tile, BK=64,
// global_load_lds width=16, XOR-swizzled LDS chunks.  (unchanged from R3)
// ---------------------------------------------------------------------------
__global__ __launch_bounds__(256)
void proj_gemm3_kernel(const unsigned short* __restrict__ Xall,
                       const unsigned short* __restrict__ Wall,
                       unsigned short* __restrict__ Call) {
    __shared__ unsigned short As[128 * 64];
    __shared__ unsigned short Bs[128 * 64];

    const int z = blockIdx.z;
    const unsigned short* X = Xall + (size_t)z * M_ROWS * DM;
    const unsigned short* W = Wall + (size_t)z * DM * DM;
    unsigned short* C = Call + (size_t)z * M_ROWS * DM;

    const int tid  = threadIdx.x;
    const int wave = tid >> 6;
    const int lane = tid & 63;
    const int l32  = lane & 31;
    const int s    = lane >> 5;
    const int m0 = blockIdx.x * 128;
    const int n0 = blockIdx.y * 128;
    const int wm = (wave >> 1) * 64;
    const int wn = (wave & 1) * 64;

    const int r8 = lane >> 3;
    const int sc = (lane & 7) ^ r8;

    f32x16 acc[2][2];
#pragma unroll
    for (int mi = 0; mi < 2; ++mi)
#pragma unroll
        for (int ni = 0; ni < 2; ++ni)
#pragma unroll
            for (int r = 0; r < 16; ++r) acc[mi][ni][r] = 0.f;

    for (int k0 = 0; k0 < DM; k0 += 64) {
#pragma unroll
        for (int i = 0; i < 4; ++i) {
            const int r = i * 32 + wave * 8 + r8;
            async_ld16(X + (size_t)(m0 + r) * DM + k0 + sc * 8,
                       (char*)As + i * 4096 + wave * 1024);
            async_ld16(W + (size_t)(n0 + r) * DM + k0 + sc * 8,
                       (char*)Bs + i * 4096 + wave * 1024);
        }
        __syncthreads();

#pragma unroll
        for (int ch = 0; ch < 4; ++ch) {
            bf16x8 af[2], bfr[2];
#pragma unroll
            for (int mi = 0; mi < 2; ++mi) {
                const int row = wm + mi * 32 + l32;
                af[mi] = *(const bf16x8*)&As[row * 64 + (((2 * ch + s) ^ (row & 7)) * 8)];
            }
#pragma unroll
            for (int ni = 0; ni < 2; ++ni) {
                const int row = wn + ni * 32 + l32;
                bfr[ni] = *(const bf16x8*)&Bs[row * 64 + (((2 * ch + s) ^ (row & 7)) * 8)];
            }
#pragma unroll
            for (int mi = 0; mi < 2; ++mi)
#pragma unroll
                for (int ni = 0; ni < 2; ++ni)
                    acc[mi][ni] = __builtin_amdgcn_mfma_f32_32x32x16_bf16(
                        af[mi], bfr[ni], acc[mi][ni], 0, 0, 0);
        }
        __syncthreads();
    }

    const float scale = (z == 0) ? SCALE_Q : 1.0f;
#pragma unroll
    for (int mi = 0; mi < 2; ++mi)
#pragma unroll
        for (int ni = 0; ni < 2; ++ni)
#pragma unroll
            for (int r = 0; r < 16; ++r) {
                const int row = m0 + wm + mi * 32 + (r & 3) + 8 * (r >> 2) + 4 * s;
                const int col = n0 + wn + ni * 32 + l32;
                C[(size_t)row * DM + col] = f2bf(acc[mi][ni][r] * scale);
            }
}

// ---------------------------------------------------------------------------
// Kernel 3: V re-tile: Vp[4096][1024] -> Vt[(b*16+h)*64+d][2048], plain
// per-head transpose.
// ---------------------------------------------------------------------------
__global__ __launch_bounds__(256)
void vtrans_kernel(const unsigned short* __restrict__ Vp,
                   unsigned short* __restrict__ Vt) {
    __shared__ unsigned short Ls[64 * 72];
    const int tr = blockIdx.x;   // token tile (64 tokens)
    const int h  = blockIdx.y;   // head
    const int tid = threadIdx.x;

#pragma unroll
    for (int i = 0; i < 2; ++i) {
        const int id = i * 256 + tid;      // 0..511
        const int r = id >> 3, c = id & 7;
        bf16x8 v8 = *(const bf16x8*)&Vp[(size_t)(tr * 64 + r) * DM + h * 64 + c * 8];
        *(bf16x8*)&Ls[r * 72 + ((c ^ (r & 7)) * 8)] = v8;
    }
    __syncthreads();

    const int b = tr >> 5;
    const int col0 = (tr & 31) * 64;
#pragma unroll
    for (int i = 0; i < 2; ++i) {
        const int id = i * 256 + tid;
        const int d = id >> 3, c2 = id & 7;
        unsigned short tmp[8];
#pragma unroll
        for (int j = 0; j < 8; ++j) {
            const int t = c2 * 8 + j;
            tmp[j] = Ls[t * 72 + (((d >> 3) ^ (t & 7)) * 8) + (d & 7)];
        }
        *(bf16x8*)&Vt[(size_t)((b * NH + h) * DEPTH + d) * S_LEN + col0 + c2 * 8] =
            *(const bf16x8*)tmp;
    }
}

// ---------------------------------------------------------------------------
// Kernel 4: attention, transposed form. One wave (64 threads) owns 64 q-rows.
// S^T = K Q^T  (A = K-frags from LDS, B = Q-frags in registers),
// O^T = V^T P^T (A = Vt-frags from LDS, B = P-frags via per-wave Ps[q][t]).
// Double-buffered K/V staging with manual vmcnt(16); no __syncthreads at all.
// R5 fix: prefetch K address was dropping the sc*8 column offset (R4 bug).
// ---------------------------------------------------------------------------
__global__ __launch_bounds__(64)
void attn4_kernel(const unsigned short* __restrict__ Qp,
                  const unsigned short* __restrict__ Kp,
                  const unsigned short* __restrict__ Vt,
                  float* __restrict__ out) {
    __shared__ __align__(16) char smem[40960];
    unsigned short* Ks = (unsigned short*)smem;              // [2][64*64]
    unsigned short* Vs = (unsigned short*)(smem + 16384);    // [2][64*64]
    unsigned short* Ps = (unsigned short*)(smem + 32768);    // [64*64]

    const int lane = threadIdx.x & 63;
    const int l32  = lane & 31;
    const int s    = lane >> 5;
    const int q0 = blockIdx.x * 64;
    const int h  = blockIdx.y;
    const int b  = blockIdx.z;

    const int r8 = lane >> 3;
    const int sc = (lane & 7) ^ r8;

    const unsigned short* Kg = Kp + (size_t)(b * S_LEN) * DM + h * DEPTH;
    const unsigned short* Vg = Vt + (size_t)((b * NH + h) * DEPTH) * S_LEN;

    // Q B-frags (n = q = l32 within subtile, k = d = ch*16 + s*8 + j), prescaled
    bf16x8 qf[2][4];
#pragma unroll
    for (int nq = 0; nq < 2; ++nq) {
        const unsigned short* p =
            Qp + (size_t)(b * S_LEN + q0 + nq * 32 + l32) * DM + h * DEPTH;
#pragma unroll
        for (int ch = 0; ch < 4; ++ch)
            qf[nq][ch] = *(const bf16x8*)(p + ch * 16 + s * 8);
    }

    f32x16 oacc[2][2];   // [db][nq]
    float lacc[2] = {0.f, 0.f};
#pragma unroll
    for (int db = 0; db < 2; ++db)
#pragma unroll
        for (int nq = 0; nq < 2; ++nq)
#pragma unroll
            for (int r = 0; r < 16; ++r) oacc[db][nq][r] = 0.f;

    // prologue: stage tile 0 into buffer 0 (K rows = tokens, V rows = d)
#pragma unroll
    for (int i = 0; i < 8; ++i) {
        async_ld16(Kg + (size_t)(i * 8 + r8) * DM + sc * 8, (char*)Ks + i * 1024);
        async_ld16(Vg + (size_t)(i * 8 + r8) * S_LEN + sc * 8, (char*)Vs + i * 1024);
    }

    for (int it = 0; it < S_LEN / 64; ++it) {
        const int buf = it & 1;
        if (it < S_LEN / 64 - 1) {
            const int t1 = (it + 1) * 64;
            char* kd = (char*)Ks + (buf ^ 1) * 8192;
            char* vd = (char*)Vs + (buf ^ 1) * 8192;
#pragma unroll
            for (int i = 0; i < 8; ++i) {
                async_ld16(Kg + (size_t)(t1 + i * 8 + r8) * DM + sc * 8,
                           kd + i * 1024);
                async_ld16(Vg + (size_t)(i * 8 + r8) * S_LEN + t1 + sc * 8,
                           vd + i * 1024);
            }
            __builtin_amdgcn_s_waitcnt(0x4F70);   // vmcnt(16): drain tile `it`
        } else {
            __builtin_amdgcn_s_waitcnt(0x0F70);   // vmcnt(0): drain last tile
        }
        __builtin_amdgcn_sched_barrier(0);

        const unsigned short* Kb = Ks + buf * 4096;
        const unsigned short* Vb = Vs + buf * 4096;

        // S^T = K Q^T, then exp2 + pack into Ps[q][t] (XOR-swizzled 8-chunks)
#pragma unroll
        for (int tb = 0; tb < 2; ++tb) {
            f32x16 s0, s1;
#pragma unroll
            for (int r = 0; r < 16; ++r) { s0[r] = 0.f; s1[r] = 0.f; }
            const int trow = tb * 32 + l32;
#pragma unroll
            for (int ch = 0; ch < 4; ++ch) {
                bf16x8 kf = *(const bf16x8*)
                    &Kb[trow * 64 + (((2 * ch + s) ^ (trow & 7)) * 8)];
                s0 = __builtin_amdgcn_mfma_f32_32x32x16_bf16(kf, qf[0][ch], s0, 0, 0, 0);
                s1 = __builtin_amdgcn_mfma_f32_32x32x16_bf16(kf, qf[1][ch], s1, 0, 0, 0);
            }
#pragma unroll
            for (int nq = 0; nq < 2; ++nq) {
                const int qq = nq * 32 + l32;
#pragma unroll
                for (int a = 0; a < 4; ++a) {
                    union { float f; unsigned u; } e0, e1, e2, e3;
                    e0.f = __builtin_amdgcn_exp2f(nq ? s1[4 * a + 0] : s0[4 * a + 0]);
                    e1.f = __builtin_amdgcn_exp2f(nq ? s1[4 * a + 1] : s0[4 * a + 1]);
                    e2.f = __builtin_amdgcn_exp2f(nq ? s1[4 * a + 2] : s0[4 * a + 2]);
                    e3.f = __builtin_amdgcn_exp2f(nq ? s1[4 * a + 3] : s0[4 * a + 3]);
                    union { unsigned u; float f; } t0, t1, t2, t3;
                    t0.u = e0.u & 0xFFFF0000u; t1.u = e1.u & 0xFFFF0000u;
                    t2.u = e2.u & 0xFFFF0000u; t3.u = e3.u & 0xFFFF0000u;
                    lacc[nq] += (t0.f + t1.f) + (t2.f + t3.f);
                    const int slot = (4 * tb + a) ^ (qq & 7);
                    *(unsigned*)&Ps[qq * 64 + slot * 8 + 4 * s] =
                        (e0.u >> 16) | (e1.u & 0xFFFF0000u);
                    *(unsigned*)&Ps[qq * 64 + slot * 8 + 4 * s + 2] =
                        (e2.u >> 16) | (e3.u & 0xFFFF0000u);
                }
            }
        }
        __builtin_amdgcn_sched_barrier(0);

        // O^T += V^T P^T
#pragma unroll
        for (int ch = 0; ch < 4; ++ch) {
            bf16x8 pf0 = *(const bf16x8*)
                &Ps[l32 * 64 + (((2 * ch + s) ^ (l32 & 7)) * 8)];
            bf16x8 pf1 = *(const bf16x8*)
                &Ps[(32 + l32) * 64 + (((2 * ch + s) ^ (l32 & 7)) * 8)];
#pragma unroll
            for (int db = 0; db < 2; ++db) {
                const int drow = db * 32 + l32;
                bf16x8 vf = *(const bf16x8*)
                    &Vb[drow * 64 + (((2 * ch + s) ^ (drow & 7)) * 8)];
                oacc[db][0] = __builtin_amdgcn_mfma_f32_32x32x16_bf16(
                    vf, pf0, oacc[db][0], 0, 0, 0);
                oacc[db][1] = __builtin_amdgcn_mfma_f32_32x32x16_bf16(
                    vf, pf1, oacc[db][1], 0, 0, 0);
            }
        }
        __builtin_amdgcn_sched_barrier(0);
    }

    // finalize l per q (t-halves live in opposite lane halves)
    const float l0 = lacc[0] + __shfl_xor(lacc[0], 32, 64);
    const float l1 = lacc[1] + __shfl_xor(lacc[1], 32, 64);
    const float inv0 = 1.0f / l0, inv1 = 1.0f / l1;

    // epilogue: O^T (col=q, row=d) -> LDS transpose -> coalesced fp32 stores
    __builtin_amdgcn_s_waitcnt(0xC07F);   // lgkmcnt(0): all LDS reads returned
    __builtin_amdgcn_sched_barrier(0);
    float* Of = (float*)(smem + 16384);   // 64 x 68 floats (over Vs+Ps)
#pragma unroll
    for (int db = 0; db < 2; ++db)
#pragma unroll
        for (int nq = 0; nq < 2; ++nq) {
            const int qq = nq * 32 + l32;
            const float inv = nq ? inv1 : inv0;
#pragma unroll
            for (int r = 0; r < 16; ++r) {
                const int d = db * 32 + (r & 3) + 8 * (r >> 2) + 4 * s;
                Of[qq * 68 + d] = oacc[db][nq][r] * inv;
            }
        }
    __builtin_amdgcn_sched_barrier(0);
#pragma unroll
    for (int i = 0; i < 16; ++i) {
        const int row = i * 4 + (lane >> 4);
        const int c4 = lane & 15;
        float4 v = *(const float4*)&Of[row * 68 + c4 * 4];
        *(float4*)&out[(size_t)(b * S_LEN + q0 + row) * DM + h * DEPTH + c4 * 4] = v;
    }
}

// ===========================================================================
// FALLBACK PATH (round-1 proven kernels, used only if ws is too small)
// ===========================================================================
#define LDK 72

__global__ __launch_bounds__(256)
void proj_gemm_kernel(const float* __restrict__ q, const float* __restrict__ k,
                      const float* __restrict__ v, const float* __restrict__ wq,
                      const float* __restrict__ wk, const float* __restrict__ wv,
                      unsigned short* __restrict__ Qp, unsigned short* __restrict__ Kp,
                      unsigned short* __restrict__ Vp) {
    __shared__ unsigned short As[128 * LDK];
    __shared__ unsigned short Bs[128 * LDK];

    const int z = blockIdx.z;
    const float* __restrict__ X = (z == 0) ? q : (z == 1) ? k : v;
    const float* __restrict__ W = (z == 0) ? wq : (z == 1) ? wk : wv;
    unsigned short* __restrict__ C = (z == 0) ? Qp : (z == 1) ? Kp : Vp;

    const int tid  = threadIdx.x;
    const int wave = tid >> 6;
    const int lane = tid & 63;
    const int quad = lane >> 4;
    const int l16  = lane & 15;
    const int m0 = blockIdx.x * 128;
    const int n0 = blockIdx.y * 128;
    const int wm = (wave >> 1) * 64;
    const int wn = (wave & 1) * 64;

    f32x4 acc[4][4];
#pragma unroll
    for (int mt = 0; mt < 4; ++mt)
#pragma unroll
        for (int nt = 0; nt < 4; ++nt)
            acc[mt][nt] = (f32x4){0.f, 0.f, 0.f, 0.f};

    for (int k0 = 0; k0 < DM; k0 += 64) {
#pragma unroll
        for (int vv = 0; vv < 8; ++vv) {
            int vecid = tid + 256 * vv;
            int r  = vecid >> 4;
            int c4 = vecid & 15;
            const float4 xa = *(const float4*)&X[(size_t)(m0 + r) * DM + k0 + c4 * 4];
            ushort4 pa;
            pa.x = f2bf(xa.x); pa.y = f2bf(xa.y); pa.z = f2bf(xa.z); pa.w = f2bf(xa.w);
            *(ushort4*)&As[r * LDK + c4 * 4] = pa;
            const float4 xb = *(const float4*)&W[(size_t)(n0 + r) * DM + k0 + c4 * 4];
            ushort4 pb;
            pb.x = f2bf(xb.x); pb.y = f2bf(xb.y); pb.z = f2bf(xb.z); pb.w = f2bf(xb.w);
            *(ushort4*)&Bs[r * LDK + c4 * 4] = pb;
        }
        __syncthreads();

#pragma unroll
        for (int kc = 0; kc < 2; ++kc) {
            bf16x8 af[4], bfr[4];
#pragma unroll
            for (int mt = 0; mt < 4; ++mt)
                af[mt] = *(const bf16x8*)&As[(wm + mt * 16 + l16) * LDK + kc * 32 + quad * 8];
#pragma unroll
            for (int nt = 0; nt < 4; ++nt)
                bfr[nt] = *(const bf16x8*)&Bs[(wn + nt * 16 + l16) * LDK + kc * 32 + quad * 8];
#pragma unroll
            for (int mt = 0; mt < 4; ++mt)
#pragma unroll
                for (int nt = 0; nt < 4; ++nt)
                    acc[mt][nt] = __builtin_amdgcn_mfma_f32_16x16x32_bf16(
                        af[mt], bfr[nt], acc[mt][nt], 0, 0, 0);
        }
        __syncthreads();
    }

#pragma unroll
    for (int mt = 0; mt < 4; ++mt)
#pragma unroll
        for (int nt = 0; nt < 4; ++nt)
#pragma unroll
            for (int r = 0; r < 4; ++r) {
                int row = m0 + wm + mt * 16 + quad * 4 + r;
                int col = n0 + wn + nt * 16 + l16;
                C[(size_t)row * DM + col] = f2bf(acc[mt][nt][r]);
            }
}

__global__ __launch_bounds__(256)
void attn_kernel(const unsigned short* __restrict__ Qp,
                 const unsigned short* __restrict__ Kp,
                 const unsigned short* __restrict__ Vp,
                 float* __restrict__ out) {
    __shared__ unsigned short Ks[64 * LDK];
    __shared__ unsigned short Vtl[64 * LDK];
    __shared__ unsigned short Ps[4 * 16 * LDK];

    const int tid  = threadIdx.x;
    const int wave = tid >> 6;
    const int lane = tid & 63;
    const int quad = lane >> 4;
    const int l16  = lane & 15;
    const int q0 = blockIdx.x * 64;
    const int h  = blockIdx.y;
    const int b  = blockIdx.z;
    const int wbase = wave * 16 * LDK;

    bf16x8 qf[2];
    {
        size_t row = (size_t)b * S_LEN + q0 + wave * 16 + l16;
        const unsigned short* p = Qp + row * DM + h * DEPTH;
        qf[0] = *(const bf16x8*)(p + quad * 8);
        qf[1] = *(const bf16x8*)(p + 32 + quad * 8);
    }

    float m_i[4], l_i[4];
    f32x4 accO[4];
#pragma unroll
    for (int r = 0; r < 4; ++r) { m_i[r] = -1e30f; l_i[r] = 0.f; }
#pragma unroll
    for (int f = 0; f < 4; ++f) accO[f] = (f32x4){0.f, 0.f, 0.f, 0.f};

    for (int t0 = 0; t0 < S_LEN; t0 += 64) {
#pragma unroll
        for (int vv = 0; vv < 2; ++vv) {
            int vecid = tid + 256 * vv;
            int r  = vecid >> 3;
            int cv = vecid & 7;
            size_t grow = (size_t)(b * S_LEN + t0 + r) * DM + h * DEPTH + cv * 8;
            *(bf16x8*)&Ks[r * LDK + cv * 8] = *(const bf16x8*)(Kp + grow);
            bf16x8 vvv = *(const bf16x8*)(Vp + grow);
#pragma unroll
            for (int j = 0; j < 8; ++j)
                Vtl[(cv * 8 + j) * LDK + r] = ((const unsigned short*)&vvv)[j];
        }
        __syncthreads();

        f32x4 sc4[4];
#pragma unroll
        for (int nt = 0; nt < 4; ++nt) {
            f32x4 a = (f32x4){0.f, 0.f, 0.f, 0.f};
            bf16x8 kf0 = *(const bf16x8*)&Ks[(nt * 16 + l16) * LDK + quad * 8];
            bf16x8 kf1 = *(const bf16x8*)&Ks[(nt * 16 + l16) * LDK + 32 + quad * 8];
            a = __builtin_amdgcn_mfma_f32_16x16x32_bf16(qf[0], kf0, a, 0, 0, 0);
            a = __builtin_amdgcn_mfma_f32_16x16x32_bf16(qf[1], kf1, a, 0, 0, 0);
            sc4[nt] = a;
        }
#pragma unroll
        for (int nt = 0; nt < 4; ++nt)
#pragma unroll
            for (int r = 0; r < 4; ++r) sc4[nt][r] *= 0.125f;

#pragma unroll
        for (int r = 0; r < 4; ++r) {
            float mx = fmaxf(fmaxf(sc4[0][r], sc4[1][r]), fmaxf(sc4[2][r], sc4[3][r]));
#pragma unroll
            for (int off = 1; off < 16; off <<= 1)
                mx = fmaxf(mx, __shfl_xor(mx, off, 64));
            float mnew = fmaxf(m_i[r], mx);
            float alpha = __expf(m_i[r] - mnew);
            float rs = 0.f;
#pragma unroll
            for (int nt = 0; nt < 4; ++nt) {
                float p = __expf(sc4[nt][r] - mnew);
                sc4[nt][r] = p;
                rs += p;
            }
#pragma unroll
            for (int off = 1; off < 16; off <<= 1)
                rs += __shfl_xor(rs, off, 64);
            l_i[r] = l_i[r] * alpha + rs;
            m_i[r] = mnew;
#pragma unroll
            for (int f = 0; f < 4; ++f) accO[f][r] *= alpha;
        }

#pragma unroll
        for (int nt = 0; nt < 4; ++nt)
#pragma unroll
            for (int r = 0; r < 4; ++r)
                Ps[wbase + (quad * 4 + r) * LDK + nt * 16 + l16] = f2bf(sc4[nt][r]);
        __syncthreads();

        bf16x8 pf0 = *(const bf16x8*)&Ps[wbase + l16 * LDK + quad * 8];
        bf16x8 pf1 = *(const bf16x8*)&Ps[wbase + l16 * LDK + 32 + quad * 8];
#pragma unroll
        for (int f = 0; f < 4; ++f) {
            bf16x8 vf0 = *(const bf16x8*)&Vtl[(f * 16 + l16) * LDK + quad * 8];
            bf16x8 vf1 = *(const bf16x8*)&Vtl[(f * 16 + l16) * LDK + 32 + quad * 8];
            accO[f] = __builtin_amdgcn_mfma_f32_16x16x32_bf16(pf0, vf0, accO[f], 0, 0, 0);
            accO[f] = __builtin_amdgcn_mfma_f32_16x16x32_bf16(pf1, vf1, accO[f], 0, 0, 0);
        }
        __syncthreads();
    }

#pragma unroll
    for (int f = 0; f < 4; ++f)
#pragma unroll
        for (int r = 0; r < 4; ++r) {
            size_t row = (size_t)b * S_LEN + q0 + wave * 16 + quad * 4 + r;
            out[row * DM + h * DEPTH + f * 16 + l16] = accO[f][r] / l_i[r];
        }
}

// ---------------------------------------------------------------------------
extern "C" void kernel_launch(void* const* d_in, const int* in_sizes, int n_in,
                              void* d_out, int out_size, void* d_ws, size_t ws_size,
                              hipStream_t stream) {
    const float* q  = (const float*)d_in[0];
    const float* k  = (const float*)d_in[1];
    const float* v  = (const float*)d_in[2];
    const float* wq = (const float*)d_in[3];
    const float* wk = (const float*)d_in[4];
    const float* wv = (const float*)d_in[5];
    float* out = (float*)d_out;

    unsigned short* ws = (unsigned short*)d_ws;
    const size_t NPROJ = (size_t)M_ROWS * DM;   // 4,194,304
    const size_t NW    = (size_t)DM * DM;       // 1,048,576

    const size_t need = (3 * NPROJ + 3 * NW + 3 * NPROJ) * sizeof(unsigned short);

    if (ws_size >= need) {
        unsigned short* Xbf = ws;
        unsigned short* Wbf = ws + 3 * NPROJ;
        unsigned short* Cp  = ws + 3 * NPROJ + 3 * NW;
        unsigned short* Qp  = Cp;
        unsigned short* Kp  = Cp + NPROJ;
        unsigned short* Vp  = Cp + 2 * NPROJ;
        unsigned short* Vt  = ws;   // overlays Xbf (dead after GEMM)

        convert_kernel<<<dim3(256, 6), 256, 0, stream>>>(q, k, v, wq, wk, wv, Xbf);
        proj_gemm3_kernel<<<dim3(M_ROWS / 128, DM / 128, 3), 256, 0, stream>>>(Xbf, Wbf, Cp);
        vtrans_kernel<<<dim3(M_ROWS / 64, NH), 256, 0, stream>>>(Vp, Vt);
        attn4_kernel<<<dim3(S_LEN / 64, NH, B_SZ), 64, 0, stream>>>(Qp, Kp, Vt, out);
    } else {
        unsigned short* Qp = ws;
        unsigned short* Kp = ws + NPROJ;
        unsigned short* Vp = ws + 2 * NPROJ;
        proj_gemm_kernel<<<dim3(M_ROWS / 128, DM / 128, 3), 256, 0, stream>>>(
            q, k, v, wq, wk, wv, Qp, Kp, Vp);
        attn_kernel<<<dim3(S_LEN / 64, NH, B_SZ), 256, 0, stream>>>(Qp, Kp, Vp, out);
    }
}

// Round 8
// 198.777 us; speedup vs baseline: 1.0738x; 1.0738x over previous
//
#include <hip/hip_runtime.h>
#include <hip/hip_bf16.h>
#include <stdint.h>

// Sizes (fixed by the problem)
#define B_SZ 2
#define S_LEN 2048
#define DM 1024
#define NH 16
#define DEPTH 64
#define M_ROWS (B_SZ * S_LEN)   // 4096
#define SCALE_Q 0.1803368801111144f   // log2(e)/sqrt(DEPTH), folded into Q proj

typedef __attribute__((ext_vector_type(8))) short bf16x8;    // 8 bf16 = 4 VGPRs
typedef __attribute__((ext_vector_type(4))) float f32x4;     // 16x16 C/D frag
typedef __attribute__((ext_vector_type(16))) float f32x16;   // 32x32 C/D frag

__device__ __forceinline__ unsigned short f2bf(float x) {
    union { float f; unsigned u; } a; a.f = x;
    unsigned r = a.u + 0x7FFF + ((a.u >> 16) & 1);   // RTNE
    return (unsigned short)(r >> 16);
}

__device__ __forceinline__ bf16x8 u4_to_bf8(uint4 u) {
    union { uint4 a; bf16x8 b; } c; c.a = u; return c.b;   // value bitcast
}

// async global->LDS, 16B per lane. LDS dest = wave-uniform base + lane*16.
__device__ __forceinline__ void async_ld16(const unsigned short* g, void* l) {
    __builtin_amdgcn_global_load_lds(
        (const __attribute__((address_space(1))) void*)g,
        (__attribute__((address_space(3))) void*)l,
        16, 0, 0);
}

// ===========================================================================
// FAST PATH
// ===========================================================================

// ---------------------------------------------------------------------------
// Kernel 1: fp32 -> bf16 convert (RTNE) of q,k,v,wq,wk,wv into ws.
// ---------------------------------------------------------------------------
__global__ __launch_bounds__(256)
void convert_kernel(const float* __restrict__ q, const float* __restrict__ k,
                    const float* __restrict__ v, const float* __restrict__ wq,
                    const float* __restrict__ wk, const float* __restrict__ wv,
                    unsigned short* __restrict__ dst) {
    const int z = blockIdx.y;
    const float* src = (z == 0) ? q : (z == 1) ? k : (z == 2) ? v
                     : (z == 3) ? wq : (z == 4) ? wk : wv;
    const size_t n4  = (z < 3) ? ((size_t)M_ROWS * DM / 4) : ((size_t)DM * DM / 4);
    const size_t off = (z < 3) ? ((size_t)z * M_ROWS * DM)
                               : ((size_t)3 * M_ROWS * DM + (size_t)(z - 3) * DM * DM);
    unsigned short* d = dst + off;
    const size_t stride = (size_t)gridDim.x * blockDim.x;
    for (size_t i = (size_t)blockIdx.x * blockDim.x + threadIdx.x; i < n4; i += stride) {
        float4 x = ((const float4*)src)[i];
        ushort4 p;
        p.x = f2bf(x.x); p.y = f2bf(x.y); p.z = f2bf(x.z); p.w = f2bf(x.w);
        ((ushort4*)d)[i] = p;
    }
}

// ---------------------------------------------------------------------------
// Kernel 2: bf16 NT GEMM with 32x32x16 MFMA. 128x128 tile, BK=64,
// global_load_lds width=16, XOR-swizzled LDS chunks.  (unchanged from R3)
// ---------------------------------------------------------------------------
__global__ __launch_bounds__(256)
void proj_gemm3_kernel(const unsigned short* __restrict__ Xall,
                       const unsigned short* __restrict__ Wall,
                       unsigned short* __restrict__ Call) {
    __shared__ unsigned short As[128 * 64];
    __shared__ unsigned short Bs[128 * 64];

    const int z = blockIdx.z;
    const unsigned short* X = Xall + (size_t)z * M_ROWS * DM;
    const unsigned short* W = Wall + (size_t)z * DM * DM;
    unsigned short* C = Call + (size_t)z * M_ROWS * DM;

    const int tid  = threadIdx.x;
    const int wave = tid >> 6;
    const int lane = tid & 63;
    const int l32  = lane & 31;
    const int s    = lane >> 5;
    const int m0 = blockIdx.x * 128;
    const int n0 = blockIdx.y * 128;
    const int wm = (wave >> 1) * 64;
    const int wn = (wave & 1) * 64;

    const int r8 = lane >> 3;
    const int sc = (lane & 7) ^ r8;

    f32x16 acc[2][2];
#pragma unroll
    for (int mi = 0; mi < 2; ++mi)
#pragma unroll
        for (int ni = 0; ni < 2; ++ni)
#pragma unroll
            for (int r = 0; r < 16; ++r) acc[mi][ni][r] = 0.f;

    for (int k0 = 0; k0 < DM; k0 += 64) {
#pragma unroll
        for (int i = 0; i < 4; ++i) {
            const int r = i * 32 + wave * 8 + r8;
            async_ld16(X + (size_t)(m0 + r) * DM + k0 + sc * 8,
                       (char*)As + i * 4096 + wave * 1024);
            async_ld16(W + (size_t)(n0 + r) * DM + k0 + sc * 8,
                       (char*)Bs + i * 4096 + wave * 1024);
        }
        __syncthreads();

#pragma unroll
        for (int ch = 0; ch < 4; ++ch) {
            bf16x8 af[2], bfr[2];
#pragma unroll
            for (int mi = 0; mi < 2; ++mi) {
                const int row = wm + mi * 32 + l32;
                af[mi] = *(const bf16x8*)&As[row * 64 + (((2 * ch + s) ^ (row & 7)) * 8)];
            }
#pragma unroll
            for (int ni = 0; ni < 2; ++ni) {
                const int row = wn + ni * 32 + l32;
                bfr[ni] = *(const bf16x8*)&Bs[row * 64 + (((2 * ch + s) ^ (row & 7)) * 8)];
            }
#pragma unroll
            for (int mi = 0; mi < 2; ++mi)
#pragma unroll
                for (int ni = 0; ni < 2; ++ni)
                    acc[mi][ni] = __builtin_amdgcn_mfma_f32_32x32x16_bf16(
                        af[mi], bfr[ni], acc[mi][ni], 0, 0, 0);
        }
        __syncthreads();
    }

    const float scale = (z == 0) ? SCALE_Q : 1.0f;
#pragma unroll
    for (int mi = 0; mi < 2; ++mi)
#pragma unroll
        for (int ni = 0; ni < 2; ++ni)
#pragma unroll
            for (int r = 0; r < 16; ++r) {
                const int row = m0 + wm + mi * 32 + (r & 3) + 8 * (r >> 2) + 4 * s;
                const int col = n0 + wn + ni * 32 + l32;
                C[(size_t)row * DM + col] = f2bf(acc[mi][ni][r] * scale);
            }
}

// ---------------------------------------------------------------------------
// Kernel 3: V re-tile: Vp[4096][1024] -> Vt[(b*16+h)*64+d][2048], plain
// per-head transpose.
// ---------------------------------------------------------------------------
__global__ __launch_bounds__(256)
void vtrans_kernel(const unsigned short* __restrict__ Vp,
                   unsigned short* __restrict__ Vt) {
    __shared__ unsigned short Ls[64 * 72];
    const int tr = blockIdx.x;   // token tile (64 tokens)
    const int h  = blockIdx.y;   // head
    const int tid = threadIdx.x;

#pragma unroll
    for (int i = 0; i < 2; ++i) {
        const int id = i * 256 + tid;      // 0..511
        const int r = id >> 3, c = id & 7;
        bf16x8 v8 = *(const bf16x8*)&Vp[(size_t)(tr * 64 + r) * DM + h * 64 + c * 8];
        *(bf16x8*)&Ls[r * 72 + ((c ^ (r & 7)) * 8)] = v8;
    }
    __syncthreads();

    const int b = tr >> 5;
    const int col0 = (tr & 31) * 64;
#pragma unroll
    for (int i = 0; i < 2; ++i) {
        const int id = i * 256 + tid;
        const int d = id >> 3, c2 = id & 7;
        unsigned short tmp[8];
#pragma unroll
        for (int j = 0; j < 8; ++j) {
            const int t = c2 * 8 + j;
            tmp[j] = Ls[t * 72 + (((d >> 3) ^ (t & 7)) * 8) + (d & 7)];
        }
        *(bf16x8*)&Vt[(size_t)((b * NH + h) * DEPTH + d) * S_LEN + col0 + c2 * 8] =
            *(const bf16x8*)tmp;
    }
}

// ---------------------------------------------------------------------------
// Kernel 4 (R8): attention, transposed form, key-split x2.
// Identical structure to R7 EXCEPT the P round-trip is now aliasing-clean:
// Ps is an unsigned-int LDS region (uint2 writes, uint4 reads, value-bitcast
// to bf16x8) and compiler memory fences separate the LDS write->read phases.
// R6/R7's failure: uint writes vs short-vector reads with no fence = TBAA
// lets the compiler reorder the P reads above the P writes.
// ---------------------------------------------------------------------------
__global__ __launch_bounds__(128, 2)
void attn8_kernel(const unsigned short* __restrict__ Qp,
                  const unsigned short* __restrict__ Kp,
                  const unsigned short* __restrict__ Vt,
                  float* __restrict__ out,
                  float* __restrict__ Op1,
                  float* __restrict__ lp) {
    __shared__ __align__(16) char smem[34816];
    unsigned short* Ks = (unsigned short*)smem;              // [2][32*64]  8 KB
    unsigned short* Vs = (unsigned short*)(smem + 8192);     // [2][64*64] 16 KB
    unsigned int*   Ps = (unsigned int*)(smem + 24576);      // [2][64*20] 10 KB

    const int tid  = threadIdx.x;
    const int w    = tid >> 6;
    const int lane = tid & 63;
    const int l32  = lane & 31;
    const int s    = lane >> 5;
    const int r8   = lane >> 3;
    const int sc   = (lane & 7) ^ r8;

    const int q0 = blockIdx.x * 128 + w * 64;
    const int h  = blockIdx.y;
    const int z  = blockIdx.z;
    const int b     = z >> 1;
    const int split = z & 1;
    const int tbase = split * 1024;

    const unsigned short* Kg = Kp + (size_t)(b * S_LEN + tbase) * DM + h * DEPTH;
    const unsigned short* Vg = Vt + (size_t)((b * NH + h) * DEPTH) * S_LEN + tbase;
    float* obase = split ? Op1 : out;
    float* lbase = lp + (size_t)split * M_ROWS * NH;
    unsigned int* PsW = Ps + w * 1280;   // 64 q x 20 uints (80 B rows)

    // Q B-frags (n = q, k = d = ch*16 + s*8 + j), prescaled by log2(e)/8
    bf16x8 qf[2][4];
#pragma unroll
    for (int nq = 0; nq < 2; ++nq) {
        const unsigned short* p =
            Qp + (size_t)(b * S_LEN + q0 + nq * 32 + l32) * DM + h * DEPTH;
#pragma unroll
        for (int ch = 0; ch < 4; ++ch)
            qf[nq][ch] = *(const bf16x8*)(p + ch * 16 + s * 8);
    }

    f32x16 oacc[2][2];   // [db][nq]
    float lacc[2] = {0.f, 0.f};
#pragma unroll
    for (int db = 0; db < 2; ++db)
#pragma unroll
        for (int nq = 0; nq < 2; ++nq)
#pragma unroll
            for (int r = 0; r < 16; ++r) oacc[db][nq][r] = 0.f;

    // prologue: K tile 0 (2 issues/wave), V pair 0 (4 issues/wave)
#pragma unroll
    for (int i = 0; i < 2; ++i)
        async_ld16(Kg + (size_t)(w * 16 + i * 8 + r8) * DM + sc * 8,
                   (char*)Ks + w * 2048 + i * 1024);
#pragma unroll
    for (int i = 0; i < 4; ++i)
        async_ld16(Vg + (size_t)(w * 32 + i * 8 + r8) * S_LEN + sc * 8,
                   (char*)Vs + w * 4096 + i * 1024);

    for (int it = 0; it < 32; ++it) {
        const int kb = it & 1;
        const int vb = (it >> 1) & 1;

        // Full barrier: (a) tile `it` staging visible (vmcnt(0) drain),
        // (b) the buffers about to be prefetched are no longer being read.
        __syncthreads();

        // prefetch next K tile into kb^1 (overlaps this iteration's compute)
        if (it < 31) {
            const int tk = (it + 1) * 32;
            char* kd = (char*)Ks + (kb ^ 1) * 4096 + w * 2048;
#pragma unroll
            for (int i = 0; i < 2; ++i)
                async_ld16(Kg + (size_t)(tk + w * 16 + i * 8 + r8) * DM + sc * 8,
                           kd + i * 1024);
        }
        // prefetch next V pair into vb^1 (on even iterations)
        if (!(it & 1) && it < 30) {
            const int tv = ((it >> 1) + 1) * 64;
            char* vd = (char*)Vs + (vb ^ 1) * 8192 + w * 4096;
#pragma unroll
            for (int i = 0; i < 4; ++i)
                async_ld16(Vg + (size_t)(w * 32 + i * 8 + r8) * S_LEN + tv + sc * 8,
                           vd + i * 1024);
        }

        const unsigned short* Kb = Ks + kb * 2048;
        const unsigned short* Vb = Vs + vb * 4096;
        const int vcb = (it & 1) * 4;   // which 32-key half of the V pair

        // S^T = K Q^T  (32 t x 64 q): A = K-frag, B = Q regs
        f32x16 s0, s1;
#pragma unroll
        for (int r = 0; r < 16; ++r) { s0[r] = 0.f; s1[r] = 0.f; }
#pragma unroll
        for (int ch = 0; ch < 4; ++ch) {
            bf16x8 kf = *(const bf16x8*)
                &Kb[l32 * 64 + (((2 * ch + s) ^ (l32 & 7)) * 8)];
            s0 = __builtin_amdgcn_mfma_f32_32x32x16_bf16(kf, qf[0][ch], s0, 0, 0, 0);
            s1 = __builtin_amdgcn_mfma_f32_32x32x16_bf16(kf, qf[1][ch], s1, 0, 0, 0);
        }

        // p = 2^s, truncate to bf16, l from the SAME truncated bits;
        // pack 4 t-values -> one uint2 write into Ps[q][t] (20-uint rows)
#pragma unroll
        for (int nq = 0; nq < 2; ++nq) {
            const int qq = nq * 32 + l32;
            const int xq = (qq ^ (qq >> 2)) & 3;
#pragma unroll
            for (int a = 0; a < 4; ++a) {
                union { float f; unsigned u; } e0, e1, e2, e3;
                e0.f = __builtin_amdgcn_exp2f(nq ? s1[4 * a + 0] : s0[4 * a + 0]);
                e1.f = __builtin_amdgcn_exp2f(nq ? s1[4 * a + 1] : s0[4 * a + 1]);
                e2.f = __builtin_amdgcn_exp2f(nq ? s1[4 * a + 2] : s0[4 * a + 2]);
                e3.f = __builtin_amdgcn_exp2f(nq ? s1[4 * a + 3] : s0[4 * a + 3]);
                union { unsigned u; float f; } t0, t1, t2, t3;
                t0.u = e0.u & 0xFFFF0000u; t1.u = e1.u & 0xFFFF0000u;
                t2.u = e2.u & 0xFFFF0000u; t3.u = e3.u & 0xFFFF0000u;
                lacc[nq] += (t0.f + t1.f) + (t2.f + t3.f);
                uint2 pk;
                pk.x = (e0.u >> 16) | (e1.u & 0xFFFF0000u);
                pk.y = (e2.u >> 16) | (e3.u & 0xFFFF0000u);
                *(uint2*)&PsW[qq * 20 + ((a ^ xq) * 4) + 2 * s] = pk;
            }
        }

        // Compiler-level memory fence: P writes MUST precede P reads.
        asm volatile("" ::: "memory");

        // O^T += V^T P^T : A = V-frag, B = P-frag (per-wave Ps, same types)
#pragma unroll
        for (int ch = 0; ch < 2; ++ch) {
            bf16x8 pf[2];
#pragma unroll
            for (int nq = 0; nq < 2; ++nq) {
                const int qq = nq * 32 + l32;
                const int slot = (2 * ch + s) ^ ((qq ^ (qq >> 2)) & 3);
                uint4 pu = *(const uint4*)&PsW[qq * 20 + slot * 4];
                pf[nq] = u4_to_bf8(pu);
            }
#pragma unroll
            for (int db = 0; db < 2; ++db) {
                const int drow = db * 32 + l32;
                bf16x8 vf = *(const bf16x8*)
                    &Vb[drow * 64 + (((vcb + 2 * ch + s) ^ (drow & 7)) * 8)];
                oacc[db][0] = __builtin_amdgcn_mfma_f32_32x32x16_bf16(
                    vf, pf[0], oacc[db][0], 0, 0, 0);
                oacc[db][1] = __builtin_amdgcn_mfma_f32_32x32x16_bf16(
                    vf, pf[1], oacc[db][1], 0, 0, 0);
            }
        }
        asm volatile("" ::: "memory");
    }

    // l partial per q (t-halves live in opposite lane halves)
    const float l0 = lacc[0] + __shfl_xor(lacc[0], 32, 64);
    const float l1 = lacc[1] + __shfl_xor(lacc[1], 32, 64);
    if (s == 0) {
        lbase[(size_t)(b * S_LEN + q0 + l32) * NH + h]      = l0;
        lbase[(size_t)(b * S_LEN + q0 + 32 + l32) * NH + h] = l1;
    }

    // epilogue: unnormalized O^T -> LDS transpose (4 chunks of 16 q) -> stores
    asm volatile("" ::: "memory");
    float* Of = (float*)PsW;   // 16 q x 68 floats = 4352 B <= 5120 B
#pragma unroll
    for (int c = 0; c < 4; ++c) {
        const int nq = c >> 1;
        if ((l32 >> 4) == (c & 1)) {
            const int qh = l32 & 15;
#pragma unroll
            for (int db = 0; db < 2; ++db)
#pragma unroll
                for (int m = 0; m < 4; ++m) {
                    float4 v;
                    v.x = oacc[db][nq][4 * m + 0];
                    v.y = oacc[db][nq][4 * m + 1];
                    v.z = oacc[db][nq][4 * m + 2];
                    v.w = oacc[db][nq][4 * m + 3];
                    *(float4*)&Of[qh * 68 + db * 32 + 8 * m + 4 * s] = v;
                }
        }
        asm volatile("" ::: "memory");
#pragma unroll
        for (int i = 0; i < 4; ++i) {
            const int row = i * 4 + (lane >> 4);
            const int c4 = lane & 15;
            float4 v = *(const float4*)&Of[row * 68 + c4 * 4];
            *(float4*)&obase[(size_t)(b * S_LEN + q0 + c * 16 + row) * DM
                             + h * DEPTH + c4 * 4] = v;
        }
        asm volatile("" ::: "memory");
    }
}

// ---------------------------------------------------------------------------
// Kernel 5: combine the two key-splits: out = (O0 + O1) / (l0 + l1)
// ---------------------------------------------------------------------------
__global__ __launch_bounds__(256)
void combine_kernel(float* __restrict__ out, const float* __restrict__ Op1,
                    const float* __restrict__ lp) {
    const int i4 = blockIdx.x * 256 + threadIdx.x;   // [0, 1048576)
    const int row = i4 >> 8;
    const int c4  = i4 & 255;
    const int h   = c4 >> 4;
    const float l = lp[row * NH + h] + lp[M_ROWS * NH + row * NH + h];
    const float inv = 1.0f / l;
    float4 a = ((const float4*)out)[i4];
    float4 bq = ((const float4*)Op1)[i4];
    a.x = (a.x + bq.x) * inv;
    a.y = (a.y + bq.y) * inv;
    a.z = (a.z + bq.z) * inv;
    a.w = (a.w + bq.w) * inv;
    ((float4*)out)[i4] = a;
}

// ===========================================================================
// FALLBACK PATH (round-1 proven kernels, used only if ws is too small)
// ===========================================================================
#define LDK 72

__global__ __launch_bounds__(256)
void proj_gemm_kernel(const float* __restrict__ q, const float* __restrict__ k,
                      const float* __restrict__ v, const float* __restrict__ wq,
                      const float* __restrict__ wk, const float* __restrict__ wv,
                      unsigned short* __restrict__ Qp, unsigned short* __restrict__ Kp,
                      unsigned short* __restrict__ Vp) {
    __shared__ unsigned short As[128 * LDK];
    __shared__ unsigned short Bs[128 * LDK];

    const int z = blockIdx.z;
    const float* __restrict__ X = (z == 0) ? q : (z == 1) ? k : v;
    const float* __restrict__ W = (z == 0) ? wq : (z == 1) ? wk : wv;
    unsigned short* __restrict__ C = (z == 0) ? Qp : (z == 1) ? Kp : Vp;

    const int tid  = threadIdx.x;
    const int wave = tid >> 6;
    const int lane = tid & 63;
    const int quad = lane >> 4;
    const int l16  = lane & 15;
    const int m0 = blockIdx.x * 128;
    const int n0 = blockIdx.y * 128;
    const int wm = (wave >> 1) * 64;
    const int wn = (wave & 1) * 64;

    f32x4 acc[4][4];
#pragma unroll
    for (int mt = 0; mt < 4; ++mt)
#pragma unroll
        for (int nt = 0; nt < 4; ++nt)
            acc[mt][nt] = (f32x4){0.f, 0.f, 0.f, 0.f};

    for (int k0 = 0; k0 < DM; k0 += 64) {
#pragma unroll
        for (int vv = 0; vv < 8; ++vv) {
            int vecid = tid + 256 * vv;
            int r  = vecid >> 4;
            int c4 = vecid & 15;
            const float4 xa = *(const float4*)&X[(size_t)(m0 + r) * DM + k0 + c4 * 4];
            ushort4 pa;
            pa.x = f2bf(xa.x); pa.y = f2bf(xa.y); pa.z = f2bf(xa.z); pa.w = f2bf(xa.w);
            *(ushort4*)&As[r * LDK + c4 * 4] = pa;
            const float4 xb = *(const float4*)&W[(size_t)(n0 + r) * DM + k0 + c4 * 4];
            ushort4 pb;
            pb.x = f2bf(xb.x); pb.y = f2bf(xb.y); pb.z = f2bf(xb.z); pb.w = f2bf(xb.w);
            *(ushort4*)&Bs[r * LDK + c4 * 4] = pb;
        }
        __syncthreads();

#pragma unroll
        for (int kc = 0; kc < 2; ++kc) {
            bf16x8 af[4], bfr[4];
#pragma unroll
            for (int mt = 0; mt < 4; ++mt)
                af[mt] = *(const bf16x8*)&As[(wm + mt * 16 + l16) * LDK + kc * 32 + quad * 8];
#pragma unroll
            for (int nt = 0; nt < 4; ++nt)
                bfr[nt] = *(const bf16x8*)&Bs[(wn + nt * 16 + l16) * LDK + kc * 32 + quad * 8];
#pragma unroll
            for (int mt = 0; mt < 4; ++mt)
#pragma unroll
                for (int nt = 0; nt < 4; ++nt)
                    acc[mt][nt] = __builtin_amdgcn_mfma_f32_16x16x32_bf16(
                        af[mt], bfr[nt], acc[mt][nt], 0, 0, 0);
        }
        __syncthreads();
    }

#pragma unroll
    for (int mt = 0; mt < 4; ++mt)
#pragma unroll
        for (int nt = 0; nt < 4; ++nt)
#pragma unroll
            for (int r = 0; r < 4; ++r) {
                int row = m0 + wm + mt * 16 + quad * 4 + r;
                int col = n0 + wn + nt * 16 + l16;
                C[(size_t)row * DM + col] = f2bf(acc[mt][nt][r]);
            }
}

__global__ __launch_bounds__(256)
void attn_kernel(const unsigned short* __restrict__ Qp,
                 const unsigned short* __restrict__ Kp,
                 const unsigned short* __restrict__ Vp,
                 float* __restrict__ out) {
    __shared__ unsigned short Ks[64 * LDK];
    __shared__ unsigned short Vtl[64 * LDK];
    __shared__ unsigned short Ps[4 * 16 * LDK];

    const int tid  = threadIdx.x;
    const int wave = tid >> 6;
    const int lane = tid & 63;
    const int quad = lane >> 4;
    const int l16  = lane & 15;
    const int q0 = blockIdx.x * 64;
    const int h  = blockIdx.y;
    const int b  = blockIdx.z;
    const int wbase = wave * 16 * LDK;

    bf16x8 qf[2];
    {
        size_t row = (size_t)b * S_LEN + q0 + wave * 16 + l16;
        const unsigned short* p = Qp + row * DM + h * DEPTH;
        qf[0] = *(const bf16x8*)(p + quad * 8);
        qf[1] = *(const bf16x8*)(p + 32 + quad * 8);
    }

    float m_i[4], l_i[4];
    f32x4 accO[4];
#pragma unroll
    for (int r = 0; r < 4; ++r) { m_i[r] = -1e30f; l_i[r] = 0.f; }
#pragma unroll
    for (int f = 0; f < 4; ++f) accO[f] = (f32x4){0.f, 0.f, 0.f, 0.f};

    for (int t0 = 0; t0 < S_LEN; t0 += 64) {
#pragma unroll
        for (int vv = 0; vv < 2; ++vv) {
            int vecid = tid + 256 * vv;
            int r  = vecid >> 3;
            int cv = vecid & 7;
            size_t grow = (size_t)(b * S_LEN + t0 + r) * DM + h * DEPTH + cv * 8;
            *(bf16x8*)&Ks[r * LDK + cv * 8] = *(const bf16x8*)(Kp + grow);
            bf16x8 vvv = *(const bf16x8*)(Vp + grow);
#pragma unroll
            for (int j = 0; j < 8; ++j)
                Vtl[(cv * 8 + j) * LDK + r] = ((const unsigned short*)&vvv)[j];
        }
        __syncthreads();

        f32x4 sc4[4];
#pragma unroll
        for (int nt = 0; nt < 4; ++nt) {
            f32x4 a = (f32x4){0.f, 0.f, 0.f, 0.f};
            bf16x8 kf0 = *(const bf16x8*)&Ks[(nt * 16 + l16) * LDK + quad * 8];
            bf16x8 kf1 = *(const bf16x8*)&Ks[(nt * 16 + l16) * LDK + 32 + quad * 8];
            a = __builtin_amdgcn_mfma_f32_16x16x32_bf16(qf[0], kf0, a, 0, 0, 0);
            a = __builtin_amdgcn_mfma_f32_16x16x32_bf16(qf[1], kf1, a, 0, 0, 0);
            sc4[nt] = a;
        }
#pragma unroll
        for (int nt = 0; nt < 4; ++nt)
#pragma unroll
            for (int r = 0; r < 4; ++r) sc4[nt][r] *= 0.125f;

#pragma unroll
        for (int r = 0; r < 4; ++r) {
            float mx = fmaxf(fmaxf(sc4[0][r], sc4[1][r]), fmaxf(sc4[2][r], sc4[3][r]));
#pragma unroll
            for (int off = 1; off < 16; off <<= 1)
                mx = fmaxf(mx, __shfl_xor(mx, off, 64));
            float mnew = fmaxf(m_i[r], mx);
            float alpha = __expf(m_i[r] - mnew);
            float rs = 0.f;
#pragma unroll
            for (int nt = 0; nt < 4; ++nt) {
                float p = __expf(sc4[nt][r] - mnew);
                sc4[nt][r] = p;
                rs += p;
            }
#pragma unroll
            for (int off = 1; off < 16; off <<= 1)
                rs += __shfl_xor(rs, off, 64);
            l_i[r] = l_i[r] * alpha + rs;
            m_i[r] = mnew;
#pragma unroll
            for (int f = 0; f < 4; ++f) accO[f][r] *= alpha;
        }

#pragma unroll
        for (int nt = 0; nt < 4; ++nt)
#pragma unroll
            for (int r = 0; r < 4; ++r)
                Ps[wbase + (quad * 4 + r) * LDK + nt * 16 + l16] = f2bf(sc4[nt][r]);
        __syncthreads();

        bf16x8 pf0 = *(const bf16x8*)&Ps[wbase + l16 * LDK + quad * 8];
        bf16x8 pf1 = *(const bf16x8*)&Ps[wbase + l16 * LDK + 32 + quad * 8];
#pragma unroll
        for (int f = 0; f < 4; ++f) {
            bf16x8 vf0 = *(const bf16x8*)&Vtl[(f * 16 + l16) * LDK + quad * 8];
            bf16x8 vf1 = *(const bf16x8*)&Vtl[(f * 16 + l16) * LDK + 32 + quad * 8];
            accO[f] = __builtin_amdgcn_mfma_f32_16x16x32_bf16(pf0, vf0, accO[f], 0, 0, 0);
            accO[f] = __builtin_amdgcn_mfma_f32_16x16x32_bf16(pf1, vf1, accO[f], 0, 0, 0);
        }
        __syncthreads();
    }

#pragma unroll
    for (int f = 0; f < 4; ++f)
#pragma unroll
        for (int r = 0; r < 4; ++r) {
            size_t row = (size_t)b * S_LEN + q0 + wave * 16 + quad * 4 + r;
            out[row * DM + h * DEPTH + f * 16 + l16] = accO[f][r] / l_i[r];
        }
}

// ---------------------------------------------------------------------------
extern "C" void kernel_launch(void* const* d_in, const int* in_sizes, int n_in,
                              void* d_out, int out_size, void* d_ws, size_t ws_size,
                              hipStream_t stream) {
    const float* q  = (const float*)d_in[0];
    const float* k  = (const float*)d_in[1];
    const float* v  = (const float*)d_in[2];
    const float* wq = (const float*)d_in[3];
    const float* wk = (const float*)d_in[4];
    const float* wv = (const float*)d_in[5];
    float* out = (float*)d_out;

    unsigned short* ws = (unsigned short*)d_ws;
    const size_t NPROJ = (size_t)M_ROWS * DM;   // 4,194,304
    const size_t NW    = (size_t)DM * DM;       // 1,048,576

    // fast path ws layout (ushort elements):
    //   region A [0, 3*NPROJ):       Xbf (q,k,v) during proj; then
    //                                Vt at [0,NPROJ) + Op1(fp32) at [NPROJ,3*NPROJ)
    //   region B [3NP, 3NP+3NW):     Wbf during proj; then lp (fp32, 512 KB)
    //   region C [3NP+3NW, +3NPROJ): Qp, Kp, Vp
    const size_t need = (3 * NPROJ + 3 * NW + 3 * NPROJ) * sizeof(unsigned short);

    if (ws_size >= need) {
        unsigned short* Xbf = ws;
        unsigned short* Wbf = ws + 3 * NPROJ;
        unsigned short* Cp  = ws + 3 * NPROJ + 3 * NW;
        unsigned short* Qp  = Cp;
        unsigned short* Kp  = Cp + NPROJ;
        unsigned short* Vp  = Cp + 2 * NPROJ;
        unsigned short* Vt  = ws;                    // overlays Xbf(q)
        float*          Op1 = (float*)(ws + NPROJ);  // overlays Xbf(k,v)
        float*          lp  = (float*)(ws + 3 * NPROJ);  // overlays Wbf

        convert_kernel<<<dim3(256, 6), 256, 0, stream>>>(q, k, v, wq, wk, wv, Xbf);
        proj_gemm3_kernel<<<dim3(M_ROWS / 128, DM / 128, 3), 256, 0, stream>>>(Xbf, Wbf, Cp);
        vtrans_kernel<<<dim3(M_ROWS / 64, NH), 256, 0, stream>>>(Vp, Vt);
        attn8_kernel<<<dim3(S_LEN / 128, NH, 4), 128, 0, stream>>>(
            Qp, Kp, Vt, out, Op1, lp);
        combine_kernel<<<dim3(M_ROWS * DM / 4 / 256), 256, 0, stream>>>(out, Op1, lp);
    } else {
        unsigned short* Qp = ws;
        unsigned short* Kp = ws + NPROJ;
        unsigned short* Vp = ws + 2 * NPROJ;
        proj_gemm_kernel<<<dim3(M_ROWS / 128, DM / 128, 3), 256, 0, stream>>>(
            q, k, v, wq, wk, wv, Qp, Kp, Vp);
        attn_kernel<<<dim3(S_LEN / 64, NH, B_SZ), 256, 0, stream>>>(Qp, Kp, Vp, out);
    }
}